// Round 1
// baseline (347.091 us; speedup 1.0000x reference)
//
#include <hip/hip_runtime.h>
#include <math.h>

#define Cc 1000
#define Dd 256
#define Bb 16384
#define NSs 200000
#define MOM 0.1f
#define EPSV 1e-12f

// d_out layout (floats), concat of reference return tuple
#define OUT_CENTER 0
#define OUT_SRC (Cc*Dd)                       // 256000
#define OUT_C2C (OUT_SRC + (size_t)NSs*Dd)    // 51,456,000
#define OUT_INTER (OUT_C2C + Cc*2)            // 51,458,000

// ws layout (floats)
#define WS_CHAT 0
#define WS_INVF (Cc*Dd)
#define WS_PART (Cc*Dd + Bb)                  // B*16 floats (float4 per (row,chunk))

#define NEG_BIG (-3.4e38f)

__device__ __forceinline__ void upd_top2(float& s1, int& i1, float& s2, int& i2,
                                         float s, int i) {
    // jax.lax.top_k tie semantics: larger value first; equal values -> lower index first
    if (s > s1 || (s == s1 && i < i1)) {
        s2 = s1; i2 = i1; s1 = s; i1 = i;
    } else if (s > s2 || (s == s2 && i < i2)) {
        s2 = s; i2 = i;
    }
}

// ---------------- K0: copy interdist, class2center, center_mem into out ----------------
__global__ void k_copy(const float4* __restrict__ interdist,
                       const float4* __restrict__ c2c,
                       const float4* __restrict__ cmem,
                       float4* __restrict__ out_inter,
                       float4* __restrict__ out_c2c,
                       float4* __restrict__ out_center) {
    int i = blockIdx.x * blockDim.x + threadIdx.x;
    const int n_inter = Cc * Cc * 2 / 4;   // 500000
    const int n_c2c   = Cc * 2 / 4;        // 500
    const int n_cm    = Cc * Dd / 4;       // 64000
    if (i < n_inter) {
        out_inter[i] = interdist[i];
    } else if (i < n_inter + n_c2c) {
        out_c2c[i - n_inter] = c2c[i - n_inter];
    } else if (i < n_inter + n_c2c + n_cm) {
        out_center[i - n_inter - n_c2c] = cmem[i - n_inter - n_c2c];
    }
}

// ---------------- K3: copy source_mem -> out1 (grid-stride float4) ----------------
__global__ void k_srccopy(const float4* __restrict__ src, float4* __restrict__ dst, int n4) {
    int stride = gridDim.x * blockDim.x;
    for (int i = blockIdx.x * blockDim.x + threadIdx.x; i < n4; i += stride)
        dst[i] = src[i];
}

// ---------------- K1: per-row: invf, d1-at-label -> class2center, seg-sum atomics, source lerp ----------------
__global__ void k_rows(const float* __restrict__ feat, const float* __restrict__ cmem,
                       const float* __restrict__ smem, const int* __restrict__ label,
                       const int* __restrict__ index,
                       float* __restrict__ out_center, float* __restrict__ out_src,
                       float* __restrict__ out_c2c, float* __restrict__ ws_invf) {
    int wid  = threadIdx.x >> 6;
    int lane = threadIdx.x & 63;
    int row  = blockIdx.x * 4 + wid;
    if (row >= Bb) return;

    const float4 f4 = *(const float4*)(feat + row * Dd + lane * 4);
    int lab = label[row];
    const float4 c4 = *(const float4*)(cmem + lab * Dd + lane * 4);

    float fs = f4.x*f4.x + f4.y*f4.y + f4.z*f4.z + f4.w*f4.w;
    float dt = f4.x*c4.x + f4.y*c4.y + f4.z*c4.z + f4.w*c4.w;
    float cs = c4.x*c4.x + c4.y*c4.y + c4.z*c4.z + c4.w*c4.w;
    #pragma unroll
    for (int off = 32; off; off >>= 1) {
        fs += __shfl_xor(fs, off);
        dt += __shfl_xor(dt, off);
        cs += __shfl_xor(cs, off);
    }
    float invf = 1.0f / fmaxf(sqrtf(fs), EPSV);
    if (lane == 0) {
        ws_invf[row] = invf;
        float invc = 1.0f / fmaxf(sqrtf(cs), EPSV);
        float d1 = 0.5f * (1.0f - dt * invf * invc);
        atomicAdd(out_c2c + lab * 2,     1.0f);
        atomicAdd(out_c2c + lab * 2 + 1, d1);
    }
    // segment-sum into center_new
    atomicAdd(out_center + lab * Dd + lane * 4 + 0, f4.x);
    atomicAdd(out_center + lab * Dd + lane * 4 + 1, f4.y);
    atomicAdd(out_center + lab * Dd + lane * 4 + 2, f4.z);
    atomicAdd(out_center + lab * Dd + lane * 4 + 3, f4.w);
    // source_mem row update (after the full copy)
    int idx = index[row];
    const float4 o4 = *(const float4*)(smem + (size_t)idx * Dd + lane * 4);
    float4 r;
    r.x = (1.0f - MOM) * o4.x + MOM * f4.x;
    r.y = (1.0f - MOM) * o4.y + MOM * f4.y;
    r.z = (1.0f - MOM) * o4.z + MOM * f4.z;
    r.w = (1.0f - MOM) * o4.w + MOM * f4.w;
    *(float4*)(out_src + (size_t)idx * Dd + lane * 4) = r;
}

// ---------------- K2: normalize center_new -> chat (one wave per center) ----------------
__global__ void k_chat(const float* __restrict__ out_center, float* __restrict__ chat) {
    int c = blockIdx.x;
    int lane = threadIdx.x;  // 64
    float4 v = *(const float4*)(out_center + c * Dd + lane * 4);
    float ss = v.x*v.x + v.y*v.y + v.z*v.z + v.w*v.w;
    #pragma unroll
    for (int off = 32; off; off >>= 1) ss += __shfl_xor(ss, off);
    float inv = 1.0f / fmaxf(sqrtf(ss), EPSV);
    float4 r; r.x = v.x*inv; r.y = v.y*inv; r.z = v.z*inv; r.w = v.w*inv;
    *(float4*)(chat + c * Dd + lane * 4) = r;
}

// ---------------- K4: f32 GEMM (feat x chat^T) with per-row top-2, 4-way column split ----------------
#define LDT 68   // padded LDS row stride (floats); 68*4B keeps float4 alignment, spreads banks

__global__ __launch_bounds__(256) void k_gemm(const float* __restrict__ feat,
                                              const float* __restrict__ chat,
                                              float4* __restrict__ part) {
    __shared__ float Alds[16 * LDT];
    __shared__ float Blds[16 * LDT];
    __shared__ float scr[64 * 16 * 4];

    int cc  = blockIdx.x;       // 0..3 column chunk (256 cols each)
    int rt  = blockIdx.y;       // 0..255 row tile (64 rows)
    int row0 = rt * 64;
    int tid = threadIdx.x;
    int tx = tid & 15;          // row group (4 rows)
    int ty = tid >> 4;          // col group (4 cols)
    int lrow = tid >> 2;        // staging: 0..63
    int lkq  = tid & 3;         // staging: float4 index within 16-k chunk

    float s1[4], s2[4];
    int   i1[4], i2[4];
    #pragma unroll
    for (int r = 0; r < 4; r++) { s1[r] = NEG_BIG; s2[r] = NEG_BIG; i1[r] = 0x7fffffff; i2[r] = 0x7fffffff; }

    for (int t = 0; t < 4; t++) {
        int c0 = cc * 256 + t * 64;
        float acc[4][4] = {};
        for (int kc = 0; kc < 16; kc++) {
            int k0 = kc * 16;
            // stage A tile [16k][64rows], transposed, padded
            const float4 av = *(const float4*)(feat + (row0 + lrow) * Dd + k0 + lkq * 4);
            Alds[(lkq*4 + 0) * LDT + lrow] = av.x;
            Alds[(lkq*4 + 1) * LDT + lrow] = av.y;
            Alds[(lkq*4 + 2) * LDT + lrow] = av.z;
            Alds[(lkq*4 + 3) * LDT + lrow] = av.w;
            // stage B tile [16k][64cols]
            int col = c0 + lrow;
            float4 bv = make_float4(0.f, 0.f, 0.f, 0.f);
            if (col < Cc) bv = *(const float4*)(chat + col * Dd + k0 + lkq * 4);
            Blds[(lkq*4 + 0) * LDT + lrow] = bv.x;
            Blds[(lkq*4 + 1) * LDT + lrow] = bv.y;
            Blds[(lkq*4 + 2) * LDT + lrow] = bv.z;
            Blds[(lkq*4 + 3) * LDT + lrow] = bv.w;
            __syncthreads();
            #pragma unroll
            for (int kk = 0; kk < 16; kk++) {
                float4 a4 = *(float4*)&Alds[kk * LDT + tx * 4];
                float4 b4 = *(float4*)&Blds[kk * LDT + ty * 4];
                float a[4] = {a4.x, a4.y, a4.z, a4.w};
                float b[4] = {b4.x, b4.y, b4.z, b4.w};
                #pragma unroll
                for (int r = 0; r < 4; r++)
                    #pragma unroll
                    for (int c = 0; c < 4; c++)
                        acc[r][c] += a[r] * b[c];
            }
            __syncthreads();
        }
        // fold this 64-col tile into the running per-thread top-2
        #pragma unroll
        for (int cj = 0; cj < 4; cj++) {
            int col = c0 + ty * 4 + cj;
            if (col >= Cc) continue;
            #pragma unroll
            for (int r = 0; r < 4; r++)
                upd_top2(s1[r], i1[r], s2[r], i2[r], acc[r][cj], col);
        }
    }

    // block-level merge: 16 ty-slots per row
    #pragma unroll
    for (int r = 0; r < 4; r++) {
        int row = tx * 4 + r;
        float4* slot = (float4*)&scr[(row * 16 + ty) * 4];
        *slot = make_float4(s1[r], s2[r], __int_as_float(i1[r]), __int_as_float(i2[r]));
    }
    __syncthreads();
    if (tid < 64) {
        int row = tid;
        float S1 = NEG_BIG, S2 = NEG_BIG;
        int I1 = 0x7fffffff, I2 = 0x7fffffff;
        for (int q = 0; q < 16; q++) {
            float4 v = *(float4*)&scr[(row * 16 + q) * 4];
            upd_top2(S1, I1, S2, I2, v.x, __float_as_int(v.z));
            upd_top2(S1, I1, S2, I2, v.y, __float_as_int(v.w));
        }
        part[(size_t)(row0 + row) * 4 + cc] =
            make_float4(S1, S2, __int_as_float(I1), __int_as_float(I2));
    }
}

// ---------------- K5: merge 4 column-chunk partials, scatter into interdist ----------------
__global__ void k_final(const float4* __restrict__ part, const float* __restrict__ ws_invf,
                        float* __restrict__ out_inter) {
    int row = blockIdx.x * blockDim.x + threadIdx.x;
    if (row >= Bb) return;
    float S1 = NEG_BIG, S2 = NEG_BIG;
    int I1 = 0x7fffffff, I2 = 0x7fffffff;
    #pragma unroll
    for (int q = 0; q < 4; q++) {
        float4 v = part[(size_t)row * 4 + q];
        upd_top2(S1, I1, S2, I2, v.x, __float_as_int(v.z));
        upd_top2(S1, I1, S2, I2, v.y, __float_as_int(v.w));
    }
    // d = 0.5*(1 - s*invf); top1 = largest s; inter = |d0 - d1| = 0.5*invf*(S1-S2)
    float inter = 0.5f * ws_invf[row] * (S1 - S2);
    size_t off = ((size_t)I1 * Cc + I2) * 2;
    atomicAdd(out_inter + off,     1.0f);
    atomicAdd(out_inter + off + 1, inter);
}

extern "C" void kernel_launch(void* const* d_in, const int* in_sizes, int n_in,
                              void* d_out, int out_size, void* d_ws, size_t ws_size,
                              hipStream_t stream) {
    const float* feat   = (const float*)d_in[0];
    const float* cmem   = (const float*)d_in[1];
    const float* smem   = (const float*)d_in[2];
    const float* c2c    = (const float*)d_in[3];
    const float* inter  = (const float*)d_in[4];
    const int*   label  = (const int*)d_in[5];
    const int*   index  = (const int*)d_in[6];

    float* out = (float*)d_out;
    float* out_center = out + OUT_CENTER;
    float* out_src    = out + OUT_SRC;
    float* out_c2c    = out + OUT_C2C;
    float* out_inter  = out + OUT_INTER;

    float* ws    = (float*)d_ws;
    float* chat  = ws + WS_CHAT;
    float* winvf = ws + WS_INVF;
    float4* part = (float4*)(ws + WS_PART);

    // K0: copies (interdist, class2center, center_mem baseline)
    {
        int total4 = Cc*Cc*2/4 + Cc*2/4 + Cc*Dd/4;  // 564500
        int blocks = (total4 + 255) / 256;
        k_copy<<<blocks, 256, 0, stream>>>((const float4*)inter, (const float4*)c2c,
                                           (const float4*)cmem,
                                           (float4*)out_inter, (float4*)out_c2c,
                                           (float4*)out_center);
    }
    // K3: full source_mem copy
    {
        int n4 = NSs * Dd / 4;  // 12,800,000
        k_srccopy<<<2048, 256, 0, stream>>>((const float4*)smem, (float4*)out_src, n4);
    }
    // K1: per-row work (after copies so the lerp overwrite lands last)
    k_rows<<<Bb / 4, 256, 0, stream>>>(feat, cmem, smem, label, index,
                                       out_center, out_src, out_c2c, winvf);
    // K2: normalize center_new
    k_chat<<<Cc, 64, 0, stream>>>(out_center, chat);
    // K4: GEMM + per-chunk top2 partials
    {
        dim3 grid(4, 256);
        k_gemm<<<grid, 256, 0, stream>>>(feat, chat, part);
    }
    // K5: merge partials, scatter interdist updates
    k_final<<<Bb / 256, 256, 0, stream>>>(part, winvf, out_inter);
}

// Round 2
// 295.661 us; speedup vs baseline: 1.1740x; 1.1740x over previous
//
#include <hip/hip_runtime.h>
#include <math.h>

#define Cc 1000
#define Cpad 1024
#define Dd 256
#define Bb 16384
#define NSs 200000
#define MOM 0.1f
#define EPSV 1e-12f
#define EPSC 0.10f

// d_out layout (floats), concat of reference return tuple
#define OUT_CENTER 0
#define OUT_SRC (Cc*Dd)                       // 256000
#define OUT_C2C (OUT_SRC + (size_t)NSs*Dd)    // 51,456,000
#define OUT_INTER (OUT_C2C + Cc*2)            // 51,458,000

// scratch layout INSIDE the out_src region (float offsets); consumed before k_srccopy overwrites
#define SCR_SCORES 0
#define SCR_FB ((size_t)Bb * Cpad)            // 16,777,216 floats
#define SCR_CB (SCR_FB + (size_t)Bb*Dd/2)     // + 2,097,152 = 18,874,368
// total ~19.0 M floats << 51.2 M available

// ws layout (floats)
#define WS_CHAT 0
#define WS_INVF (Cc*Dd)

#define NEG_BIG (-3.4e38f)

typedef __bf16 bf16x8 __attribute__((ext_vector_type(8)));
typedef float  f32x4  __attribute__((ext_vector_type(4)));

__device__ __forceinline__ ushort f2bf(float f) {
    uint u = __float_as_uint(f);
    u += 0x7FFFu + ((u >> 16) & 1u);   // round-to-nearest-even
    return (ushort)(u >> 16);
}

__device__ __forceinline__ void upd_top2(float& s1, int& i1, float& s2, int& i2,
                                         float s, int i) {
    // jax.lax.top_k tie semantics: larger value first; equal values -> lower index first
    if (s > s1 || (s == s1 && i < i1)) {
        s2 = s1; i2 = i1; s1 = s; i1 = i;
    } else if (s > s2 || (s == s2 && i < i2)) {
        s2 = s; i2 = i;
    }
}

// ---------------- K0: copy interdist, class2center, center_mem into out ----------------
__global__ void k_copy(const float4* __restrict__ interdist,
                       const float4* __restrict__ c2c,
                       const float4* __restrict__ cmem,
                       float4* __restrict__ out_inter,
                       float4* __restrict__ out_c2c,
                       float4* __restrict__ out_center) {
    int i = blockIdx.x * blockDim.x + threadIdx.x;
    const int n_inter = Cc * Cc * 2 / 4;
    const int n_c2c   = Cc * 2 / 4;
    const int n_cm    = Cc * Dd / 4;
    if (i < n_inter) {
        out_inter[i] = interdist[i];
    } else if (i < n_inter + n_c2c) {
        out_c2c[i - n_inter] = c2c[i - n_inter];
    } else if (i < n_inter + n_c2c + n_cm) {
        out_center[i - n_inter - n_c2c] = cmem[i - n_inter - n_c2c];
    }
}

// ---------------- K1a: per-row norms, d1@label -> c2c, seg-sum atomics, feat->bf16 ----------------
__global__ void k_rows_a(const float* __restrict__ feat, const float* __restrict__ cmem,
                         const int* __restrict__ label,
                         float* __restrict__ out_center, float* __restrict__ out_c2c,
                         float* __restrict__ ws_invf, ushort* __restrict__ fb) {
    int wid  = threadIdx.x >> 6;
    int lane = threadIdx.x & 63;
    int row  = blockIdx.x * 4 + wid;
    if (row >= Bb) return;

    const float4 f4 = *(const float4*)(feat + (size_t)row * Dd + lane * 4);
    int lab = label[row];
    const float4 c4 = *(const float4*)(cmem + (size_t)lab * Dd + lane * 4);

    // feat -> bf16 scratch
    ushort4 h;
    h.x = f2bf(f4.x); h.y = f2bf(f4.y); h.z = f2bf(f4.z); h.w = f2bf(f4.w);
    *(ushort4*)(fb + (size_t)row * Dd + lane * 4) = h;

    float fs = f4.x*f4.x + f4.y*f4.y + f4.z*f4.z + f4.w*f4.w;
    float dt = f4.x*c4.x + f4.y*c4.y + f4.z*c4.z + f4.w*c4.w;
    float cs = c4.x*c4.x + c4.y*c4.y + c4.z*c4.z + c4.w*c4.w;
    #pragma unroll
    for (int off = 32; off; off >>= 1) {
        fs += __shfl_xor(fs, off);
        dt += __shfl_xor(dt, off);
        cs += __shfl_xor(cs, off);
    }
    float invf = 1.0f / fmaxf(sqrtf(fs), EPSV);
    if (lane == 0) {
        ws_invf[row] = invf;
        float invc = 1.0f / fmaxf(sqrtf(cs), EPSV);
        float d1 = 0.5f * (1.0f - dt * invf * invc);
        atomicAdd(out_c2c + lab * 2,     1.0f);
        atomicAdd(out_c2c + lab * 2 + 1, d1);
    }
    atomicAdd(out_center + (size_t)lab * Dd + lane * 4 + 0, f4.x);
    atomicAdd(out_center + (size_t)lab * Dd + lane * 4 + 1, f4.y);
    atomicAdd(out_center + (size_t)lab * Dd + lane * 4 + 2, f4.z);
    atomicAdd(out_center + (size_t)lab * Dd + lane * 4 + 3, f4.w);
}

// ---------------- K2: normalize center_new -> chat (f32) + chat_bf16 (padded to 1024) ----------------
__global__ void k_chat(const float* __restrict__ out_center, float* __restrict__ chat,
                       ushort* __restrict__ cb) {
    int c = blockIdx.x;      // 0..1023
    int lane = threadIdx.x;  // 64
    if (c >= Cc) {
        ushort4 z; z.x = 0; z.y = 0; z.z = 0; z.w = 0;
        *(ushort4*)(cb + (size_t)c * Dd + lane * 4) = z;
        return;
    }
    float4 v = *(const float4*)(out_center + (size_t)c * Dd + lane * 4);
    float ss = v.x*v.x + v.y*v.y + v.z*v.z + v.w*v.w;
    #pragma unroll
    for (int off = 32; off; off >>= 1) ss += __shfl_xor(ss, off);
    float inv = 1.0f / fmaxf(sqrtf(ss), EPSV);
    float4 r; r.x = v.x*inv; r.y = v.y*inv; r.z = v.z*inv; r.w = v.w*inv;
    *(float4*)(chat + (size_t)c * Dd + lane * 4) = r;
    ushort4 h;
    h.x = f2bf(r.x); h.y = f2bf(r.y); h.z = f2bf(r.z); h.w = f2bf(r.w);
    *(ushort4*)(cb + (size_t)c * Dd + lane * 4) = h;
}

// ---------------- K4: bf16 MFMA GEMM, scores = feat_bf16 x chat_bf16^T -> f32 [Bb][1024] ----------------
// Per wave: 64 rows x 64 cols via 4x4 fragments of 16x16x32. No LDS: both operands are
// 16B-contiguous per lane from row-major bf16 buffers (A row = lane&15, B col = lane&15,
// k-chunk = (lane>>4)*8; A/B share the k mapping so the contraction is exact).
__global__ __launch_bounds__(256) void k_gemm(const ushort* __restrict__ fb,
                                              const ushort* __restrict__ cb,
                                              float* __restrict__ scores) {
    int wid  = threadIdx.x >> 6;
    int lane = threadIdx.x & 63;
    int rl = lane & 15;
    int kg = lane >> 4;
    int row0 = blockIdx.y * 64;
    int c0   = blockIdx.x * 256 + wid * 64;

    const ushort* fp = fb + (size_t)(row0 + rl) * Dd + kg * 8;
    const ushort* cp = cb + (size_t)(c0  + rl) * Dd + kg * 8;

    f32x4 acc[4][4];
    f32x4 z = {0.f, 0.f, 0.f, 0.f};
    #pragma unroll
    for (int mi = 0; mi < 4; mi++)
        #pragma unroll
        for (int ni = 0; ni < 4; ni++)
            acc[mi][ni] = z;

    #pragma unroll
    for (int ks = 0; ks < 8; ks++) {
        bf16x8 a[4], b[4];
        #pragma unroll
        for (int mi = 0; mi < 4; mi++)
            a[mi] = *(const bf16x8*)(fp + (size_t)mi * 16 * Dd + ks * 32);
        #pragma unroll
        for (int ni = 0; ni < 4; ni++)
            b[ni] = *(const bf16x8*)(cp + (size_t)ni * 16 * Dd + ks * 32);
        #pragma unroll
        for (int mi = 0; mi < 4; mi++)
            #pragma unroll
            for (int ni = 0; ni < 4; ni++)
                acc[mi][ni] = __builtin_amdgcn_mfma_f32_16x16x32_bf16(a[mi], b[ni], acc[mi][ni], 0, 0, 0);
    }

    // C/D layout: col = lane&15, row = (lane>>4)*4 + reg  [measured m89]
    #pragma unroll
    for (int mi = 0; mi < 4; mi++)
        #pragma unroll
        for (int ni = 0; ni < 4; ni++)
            #pragma unroll
            for (int r = 0; r < 4; r++)
                scores[(size_t)(row0 + mi*16 + kg*4 + r) * Cpad + (c0 + ni*16 + rl)] = acc[mi][ni][r];
}

// ---------------- K5: per-row exact top-2 of approx scores + f32 rescore of near-top candidates ----------------
__global__ __launch_bounds__(256) void k_sel(const float* __restrict__ scores,
                                             const float* __restrict__ feat,
                                             const float* __restrict__ chat,
                                             const float* __restrict__ ws_invf,
                                             float* __restrict__ out_inter) {
    __shared__ int cnt[4];
    __shared__ int clist[4][32];
    int wid  = threadIdx.x >> 6;
    int lane = threadIdx.x & 63;
    int row  = blockIdx.x * 4 + wid;
    if (lane == 0) cnt[wid] = 0;

    const float4* sp = (const float4*)(scores + (size_t)row * Cpad);
    float v[16];
    float s1 = NEG_BIG, s2 = NEG_BIG;
    int   i1 = 0x7fffffff, i2 = 0x7fffffff;
    #pragma unroll
    for (int j = 0; j < 4; j++) {
        float4 q = sp[j * 64 + lane];           // cols j*256 + lane*4 .. +3 (coalesced)
        int cbase = j * 256 + lane * 4;
        v[j*4+0] = q.x; v[j*4+1] = q.y; v[j*4+2] = q.z; v[j*4+3] = q.w;
        if (cbase + 0 < Cc) upd_top2(s1, i1, s2, i2, q.x, cbase + 0);
        if (cbase + 1 < Cc) upd_top2(s1, i1, s2, i2, q.y, cbase + 1);
        if (cbase + 2 < Cc) upd_top2(s1, i1, s2, i2, q.z, cbase + 2);
        if (cbase + 3 < Cc) upd_top2(s1, i1, s2, i2, q.w, cbase + 3);
    }
    // butterfly merge (disjoint column sets at every step -> no duplicate insertions)
    #pragma unroll
    for (int off = 1; off < 64; off <<= 1) {
        float ps1 = __shfl_xor(s1, off), ps2 = __shfl_xor(s2, off);
        int   pi1 = __shfl_xor(i1, off), pi2 = __shfl_xor(i2, off);
        upd_top2(s1, i1, s2, i2, ps1, pi1);
        upd_top2(s1, i1, s2, i2, ps2, pi2);
    }
    // candidates: every col with approx score within EPSC of the 2nd max
    float thr = s2 - EPSC;
    #pragma unroll
    for (int j = 0; j < 16; j++) {
        int c = (j >> 2) * 256 + lane * 4 + (j & 3);
        if (v[j] >= thr && c < Cc) {
            int slot = atomicAdd(&cnt[wid], 1);
            if (slot < 32) clist[wid][slot] = c;
        }
    }
    __syncthreads();
    int n = cnt[wid]; if (n > 32) n = 32;

    const float4 f4 = *(const float4*)(feat + (size_t)row * Dd + lane * 4);
    float S1 = NEG_BIG, S2 = NEG_BIG;
    int   I1 = 0x7fffffff, I2 = 0x7fffffff;
    for (int k = 0; k < n; k++) {
        int c = clist[wid][k];
        const float4 c4 = *(const float4*)(chat + (size_t)c * Dd + lane * 4);
        float d = f4.x*c4.x + f4.y*c4.y + f4.z*c4.z + f4.w*c4.w;
        #pragma unroll
        for (int off = 32; off; off >>= 1) d += __shfl_xor(d, off);
        upd_top2(S1, I1, S2, I2, d, c);   // order-independent result
    }
    if (lane == 0) {
        float inter = 0.5f * ws_invf[row] * (S1 - S2);
        size_t off2 = ((size_t)I1 * Cc + I2) * 2;
        atomicAdd(out_inter + off2,     1.0f);
        atomicAdd(out_inter + off2 + 1, inter);
    }
}

// ---------------- K3: copy source_mem -> out1 (grid-stride float4) ----------------
__global__ void k_srccopy(const float4* __restrict__ src, float4* __restrict__ dst, int n4) {
    int stride = gridDim.x * blockDim.x;
    for (int i = blockIdx.x * blockDim.x + threadIdx.x; i < n4; i += stride)
        dst[i] = src[i];
}

// ---------------- K1b: momentum lerp of the B touched rows ----------------
__global__ void k_rows_b(const float* __restrict__ feat, const float* __restrict__ smem,
                         const int* __restrict__ index, float* __restrict__ out_src) {
    int wid  = threadIdx.x >> 6;
    int lane = threadIdx.x & 63;
    int row  = blockIdx.x * 4 + wid;
    if (row >= Bb) return;
    int idx = index[row];
    const float4 f4 = *(const float4*)(feat + (size_t)row * Dd + lane * 4);
    const float4 o4 = *(const float4*)(smem + (size_t)idx * Dd + lane * 4);
    float4 r;
    r.x = (1.0f - MOM) * o4.x + MOM * f4.x;
    r.y = (1.0f - MOM) * o4.y + MOM * f4.y;
    r.z = (1.0f - MOM) * o4.z + MOM * f4.z;
    r.w = (1.0f - MOM) * o4.w + MOM * f4.w;
    *(float4*)(out_src + (size_t)idx * Dd + lane * 4) = r;
}

extern "C" void kernel_launch(void* const* d_in, const int* in_sizes, int n_in,
                              void* d_out, int out_size, void* d_ws, size_t ws_size,
                              hipStream_t stream) {
    const float* feat   = (const float*)d_in[0];
    const float* cmem   = (const float*)d_in[1];
    const float* smem   = (const float*)d_in[2];
    const float* c2c    = (const float*)d_in[3];
    const float* inter  = (const float*)d_in[4];
    const int*   label  = (const int*)d_in[5];
    const int*   index  = (const int*)d_in[6];

    float* out = (float*)d_out;
    float* out_center = out + OUT_CENTER;
    float* out_src    = out + OUT_SRC;
    float* out_c2c    = out + OUT_C2C;
    float* out_inter  = out + OUT_INTER;

    float* ws    = (float*)d_ws;
    float* chat  = ws + WS_CHAT;
    float* winvf = ws + WS_INVF;

    // scratch inside out_src region (fully overwritten by k_srccopy/k_rows_b afterwards)
    float*  scores = out_src + SCR_SCORES;
    ushort* fb     = (ushort*)(out_src + SCR_FB);
    ushort* cb     = (ushort*)(out_src + SCR_CB);

    // K0: baseline copies (interdist, class2center, center_mem)
    {
        int total4 = Cc*Cc*2/4 + Cc*2/4 + Cc*Dd/4;
        int blocks = (total4 + 255) / 256;
        k_copy<<<blocks, 256, 0, stream>>>((const float4*)inter, (const float4*)c2c,
                                           (const float4*)cmem,
                                           (float4*)out_inter, (float4*)out_c2c,
                                           (float4*)out_center);
    }
    // K1a: per-row norms, c2c, center atomics, feat->bf16
    k_rows_a<<<Bb / 4, 256, 0, stream>>>(feat, cmem, label, out_center, out_c2c, winvf, fb);
    // K2: normalize center_new -> chat + chat_bf16 (padded)
    k_chat<<<Cpad, 64, 0, stream>>>(out_center, chat, cb);
    // K4: MFMA GEMM -> scores
    {
        dim3 grid(4, Bb / 64);
        k_gemm<<<grid, 256, 0, stream>>>(fb, cb, scores);
    }
    // K5: top-2 + f32 rescore -> interdist atomics
    k_sel<<<Bb / 4, 256, 0, stream>>>(scores, feat, chat, winvf, out_inter);
    // K3: full source_mem copy (overwrites scratch)
    {
        int n4 = NSs * Dd / 4;
        k_srccopy<<<2048, 256, 0, stream>>>((const float4*)smem, (float4*)out_src, n4);
    }
    // K1b: momentum rows last
    k_rows_b<<<Bb / 4, 256, 0, stream>>>(feat, smem, index, out_src);
}